// Round 13
// baseline (136.958 us; speedup 1.0000x reference)
//
#include <hip/hip_runtime.h>
#include <hip/hip_bf16.h>

// Problem constants
#define BATCH   4096
#define TWO_B   8192
#define DIM     128
#define INV_TEMP 2.0f      // 1/TEMP, TEMP=0.5
// sqrt(INV_TEMP * log2(e)) folded into the stored bf16 vectors -> MFMA acc
// comes out as sim * INV_TEMP * log2(e); epilogue is a bare exp2.
#define SFOLD 1.6986436f   // sqrt(2.8853900817779268)

typedef __attribute__((ext_vector_type(8))) short bf16x8;   // 8 bf16 = 4 VGPRs
typedef __attribute__((ext_vector_type(4))) float f32x4;

#define CS 16              // col splits; each wave: 64 rows x 512 cols

// Workspace layout (bytes):
//   zb     : __hip_bfloat16[TWO_B*DIM]  [0, 2097152)   pre-scaled by SFOLD
//   rowsum : float[TWO_B]               zeroed by k_normalize
//   ps     : float[1024]                per-block possum partials
#define ZB_BYTES   (TWO_B * DIM * 2)
#define RS_OFFSET  ZB_BYTES
#define PS_OFFSET  (RS_OFFSET + TWO_B * 4)

// ---------------------------------------------------------------------------
// Kernel 1: L2-normalize rows of zi AND zj (paired), write bf16 z rows scaled
// by SFOLD, write per-block possum partial, and zero rowsum (8 floats/block).
// ---------------------------------------------------------------------------
__global__ __launch_bounds__(256) void k_normalize(const float* __restrict__ zi,
                                                   const float* __restrict__ zj,
                                                   __hip_bfloat16* __restrict__ zb,
                                                   float* __restrict__ ps,
                                                   float* __restrict__ rowsum) {
    int w = threadIdx.x >> 6;
    int lane = threadIdx.x & 63;
    int r = blockIdx.x * 4 + w;                       // [0, BATCH)

    // zero rowsum: 1024 blocks x 8 floats = 8192
    if (threadIdx.x < 8) rowsum[blockIdx.x * 8 + threadIdx.x] = 0.0f;

    float2 vi = *reinterpret_cast<const float2*>(zi + (size_t)r * DIM + lane * 2);
    float2 vj = *reinterpret_cast<const float2*>(zj + (size_t)r * DIM + lane * 2);
    float ssi = vi.x * vi.x + vi.y * vi.y;
    float ssj = vj.x * vj.x + vj.y * vj.y;
    #pragma unroll
    for (int m = 1; m < 64; m <<= 1) {
        ssi += __shfl_xor(ssi, m, 64);
        ssj += __shfl_xor(ssj, m, 64);
    }
    float invi = 1.0f / fmaxf(sqrtf(ssi), 1e-12f);
    float invj = 1.0f / fmaxf(sqrtf(ssj), 1e-12f);

    float nix = vi.x * invi, niy = vi.y * invi;
    float njx = vj.x * invj, njy = vj.y * invj;

    __hip_bfloat162 hi2, hj2;
    hi2.x = __float2bfloat16(nix * SFOLD);
    hi2.y = __float2bfloat16(niy * SFOLD);
    hj2.x = __float2bfloat16(njx * SFOLD);
    hj2.y = __float2bfloat16(njy * SFOLD);
    *reinterpret_cast<__hip_bfloat162*>(zb + (size_t)r * DIM + lane * 2) = hi2;
    *reinterpret_cast<__hip_bfloat162*>(zb + (size_t)(r + BATCH) * DIM + lane * 2) = hj2;

    // paired-diagonal dot in fp32 (unscaled)
    float d = nix * njx + niy * njy;
    #pragma unroll
    for (int m = 1; m < 64; m <<= 1) d += __shfl_xor(d, m, 64);

    __shared__ float red[4];
    if (lane == 0) red[w] = d;
    __syncthreads();
    if (threadIdx.x == 0)
        ps[blockIdx.x] = red[0] + red[1] + red[2] + red[3];
}

// ---------------------------------------------------------------------------
// Kernel 2: similarity + fused exp2/row-sum. No LDS, no barriers.
// Grid: (TWO_B/256)*CS = 512 blocks, 256 threads (4 waves). Wave w owns rows
// [rowBlock*256 + w*64, +64); all 4 waves share cols [split*512, +512) as
// 16 x 32-col tiles, REGISTER-DOUBLE-BUFFERED (bA/bB): tile k+1's 8 global
// loads issue before tile k's MFMA+epilogue, so the compiler emits counted
// vmcnt waits instead of a full drain per tile (the r6 stall).
// A-fragments (64 VGPR) live in registers for the whole kernel.
// VGPR budget: a64 + bA32 + bB32 + acc32 + psum16 ~= 190 (no spill at
// (256,2); round-8 lesson: never force occupancy via launch_bounds).
// MFMA C/D layout (m89): col = lane&15, row = (lane>>4)*4 + reg.
// ---------------------------------------------------------------------------
__global__ __launch_bounds__(256, 2) void k_sim(const __hip_bfloat16* __restrict__ zb,
                                                float* __restrict__ rowsum) {
    const int t = threadIdx.x;
    const int w = t >> 6;
    const int lane = t & 63;
    const int lo = lane & 15, hi = lane >> 4;

    const int rowBlock = blockIdx.x >> 4;        // / CS
    const int split    = blockIdx.x & (CS - 1);
    const int rowBase  = rowBlock * 256 + w * 64;
    const int colWin   = split * 512;

    const char* zbB = reinterpret_cast<const char*>(zb);

    // A fragments: a[i][ks] = 16B at row (rowBase+i*16+lo), k-chunk (ks*4+hi)
    bf16x8 a[4][4];
    #pragma unroll
    for (int i = 0; i < 4; ++i) {
        const char* rp = zbB + (size_t)(rowBase + i * 16 + lo) * 256 + hi * 16;
        #pragma unroll
        for (int ks = 0; ks < 4; ++ks)
            a[i][ks] = *reinterpret_cast<const bf16x8*>(rp + ks * 64);
    }

    float psum[4][4];
    #pragma unroll
    for (int i = 0; i < 4; ++i)
        #pragma unroll
        for (int p = 0; p < 4; ++p) psum[i][p] = 0.0f;

    bf16x8 bA[2][4], bB[2][4];

    // load one 32-col tile's B fragments into the given buffer
#define LOADB(bb, colBase)                                                     \
    {                                                                          \
        _Pragma("unroll")                                                      \
        for (int j = 0; j < 2; ++j) {                                          \
            const char* rp = zbB + (size_t)((colBase) + j * 16 + lo) * 256 +   \
                             hi * 16;                                          \
            _Pragma("unroll")                                                  \
            for (int ks = 0; ks < 4; ++ks)                                     \
                bb[j][ks] = *reinterpret_cast<const bf16x8*>(rp + ks * 64);    \
        }                                                                      \
    }

    // MFMA + fused exp2/row-partial epilogue for one 32-col tile
#define COMPUTE(bb, colBase)                                                   \
    {                                                                          \
        f32x4 acc[4][2];                                                       \
        _Pragma("unroll")                                                      \
        for (int i = 0; i < 4; ++i) {                                          \
            acc[i][0] = (f32x4){0.f, 0.f, 0.f, 0.f};                           \
            acc[i][1] = (f32x4){0.f, 0.f, 0.f, 0.f};                           \
        }                                                                      \
        _Pragma("unroll")                                                      \
        for (int ks = 0; ks < 4; ++ks)                                         \
            for (int i = 0; i < 4; ++i) {                                      \
                acc[i][0] = __builtin_amdgcn_mfma_f32_16x16x32_bf16(           \
                    a[i][ks], bb[0][ks], acc[i][0], 0, 0, 0);                  \
                acc[i][1] = __builtin_amdgcn_mfma_f32_16x16x32_bf16(           \
                    a[i][ks], bb[1][ks], acc[i][1], 0, 0, 0);                  \
            }                                                                  \
        const bool mayDiag = ((unsigned)((colBase) - rowBase) < 64u);          \
        _Pragma("unroll")                                                      \
        for (int i = 0; i < 4; ++i) {                                          \
            _Pragma("unroll")                                                  \
            for (int p = 0; p < 4; ++p) {                                      \
                int gr = rowBase + i * 16 + hi * 4 + p;                        \
                float s = 0.0f;                                                \
                _Pragma("unroll")                                              \
                for (int j = 0; j < 2; ++j) {                                  \
                    float e = exp2f(acc[i][j][p]);                             \
                    if (mayDiag && gr == (colBase) + j * 16 + lo) e = 0.0f;    \
                    s += e;                                                    \
                }                                                              \
                psum[i][p] += s;                                               \
            }                                                                  \
        }                                                                      \
    }

    LOADB(bA, colWin);
    #pragma unroll
    for (int cp = 0; cp < 8; ++cp) {
        const int c0 = colWin + cp * 64;       // bA's tile (32 cols)
        LOADB(bB, c0 + 32);                    // prefetch pair partner
        COMPUTE(bA, c0);
        if (cp < 7) LOADB(bA, c0 + 64);        // prefetch next pair's first
        COMPUTE(bB, c0 + 32);
    }
#undef LOADB
#undef COMPUTE

    // reduce over the 16 lo-lanes (distinct cols); atomic per row.
    #pragma unroll
    for (int i = 0; i < 4; ++i) {
        #pragma unroll
        for (int p = 0; p < 4; ++p) {
            float s = psum[i][p];
            s += __shfl_xor(s, 1, 64);
            s += __shfl_xor(s, 2, 64);
            s += __shfl_xor(s, 4, 64);
            s += __shfl_xor(s, 8, 64);
            if (lo == 0)
                atomicAdd(&rowsum[rowBase + i * 16 + hi * 4 + p], s);
        }
    }
}

// ---------------------------------------------------------------------------
// Kernel 3: loss = (sum_r log(rowsum[r]) - 2*INV_TEMP*possum) / TWO_B
// ---------------------------------------------------------------------------
__global__ __launch_bounds__(1024) void k_final(const float* __restrict__ rowsum,
                                                const float* __restrict__ ps,
                                                float* __restrict__ out) {
    __shared__ float redl[1024];
    __shared__ float redp[1024];
    const int t = threadIdx.x;

    float s = 0.0f;
    #pragma unroll
    for (int q = 0; q < TWO_B / 1024; ++q) s += logf(rowsum[t + q * 1024]);
    float p = ps[t];

    redl[t] = s;
    redp[t] = p;
    __syncthreads();
    #pragma unroll
    for (int off = 512; off > 0; off >>= 1) {
        if (t < off) {
            redl[t] += redl[t + off];
            redp[t] += redp[t + off];
        }
        __syncthreads();
    }
    if (t == 0)
        out[0] = (redl[0] - 2.0f * INV_TEMP * redp[0]) / (float)TWO_B;
}

// ---------------------------------------------------------------------------
extern "C" void kernel_launch(void* const* d_in, const int* in_sizes, int n_in,
                              void* d_out, int out_size, void* d_ws, size_t ws_size,
                              hipStream_t stream) {
    const float* zi = (const float*)d_in[0];
    const float* zj = (const float*)d_in[1];
    float* out = (float*)d_out;

    char* ws = (char*)d_ws;
    __hip_bfloat16* zb = (__hip_bfloat16*)ws;
    float* rowsum = (float*)(ws + RS_OFFSET);
    float* ps = (float*)(ws + PS_OFFSET);

    k_normalize<<<BATCH / 4, 256, 0, stream>>>(zi, zj, zb, ps, rowsum);
    k_sim<<<(TWO_B / 256) * CS, 256, 0, stream>>>(zb, rowsum);
    k_final<<<1, 1024, 0, stream>>>(rowsum, ps, out);
}

// Round 14
// 109.646 us; speedup vs baseline: 1.2491x; 1.2491x over previous
//
#include <hip/hip_runtime.h>
#include <hip/hip_bf16.h>

// Problem constants
#define BATCH   4096
#define TWO_B   8192
#define DIM     128
#define INV_TEMP 2.0f      // 1/TEMP, TEMP=0.5
// sqrt(INV_TEMP * log2(e)) folded into the stored bf16 vectors -> MFMA acc
// comes out as sim * INV_TEMP * log2(e); epilogue is a bare exp2.
#define SFOLD 1.6986436f   // sqrt(2.8853900817779268)

typedef __attribute__((ext_vector_type(8))) short bf16x8;   // 8 bf16 = 4 VGPRs
typedef __attribute__((ext_vector_type(4))) float f32x4;

#define CS 16              // col splits; each wave: 64 rows x 512 cols

// Workspace layout (bytes):
//   zb     : __hip_bfloat16[TWO_B*DIM]  [0, 2097152)   pre-scaled by SFOLD
//   rowsum : float[TWO_B]               zeroed by k_normalize
//   ps     : float[1024]                per-block possum partials
//   probe scratch: beyond PS (ws is >= 268 MB per the harness poison size)
#define ZB_BYTES   (TWO_B * DIM * 2)
#define RS_OFFSET  ZB_BYTES
#define PS_OFFSET  (RS_OFFSET + TWO_B * 4)
#define PR_OFFSET  (PS_OFFSET + 4096)

// ---------------------------------------------------------------------------
// Kernel 1: L2-normalize rows of zi AND zj (paired), write bf16 z rows scaled
// by SFOLD, write per-block possum partial, and zero rowsum (8 floats/block).
// ---------------------------------------------------------------------------
__global__ __launch_bounds__(256) void k_normalize(const float* __restrict__ zi,
                                                   const float* __restrict__ zj,
                                                   __hip_bfloat16* __restrict__ zb,
                                                   float* __restrict__ ps,
                                                   float* __restrict__ rowsum) {
    int w = threadIdx.x >> 6;
    int lane = threadIdx.x & 63;
    int r = blockIdx.x * 4 + w;                       // [0, BATCH)

    if (threadIdx.x < 8) rowsum[blockIdx.x * 8 + threadIdx.x] = 0.0f;

    float2 vi = *reinterpret_cast<const float2*>(zi + (size_t)r * DIM + lane * 2);
    float2 vj = *reinterpret_cast<const float2*>(zj + (size_t)r * DIM + lane * 2);
    float ssi = vi.x * vi.x + vi.y * vi.y;
    float ssj = vj.x * vj.x + vj.y * vj.y;
    #pragma unroll
    for (int m = 1; m < 64; m <<= 1) {
        ssi += __shfl_xor(ssi, m, 64);
        ssj += __shfl_xor(ssj, m, 64);
    }
    float invi = 1.0f / fmaxf(sqrtf(ssi), 1e-12f);
    float invj = 1.0f / fmaxf(sqrtf(ssj), 1e-12f);

    float nix = vi.x * invi, niy = vi.y * invi;
    float njx = vj.x * invj, njy = vj.y * invj;

    __hip_bfloat162 hi2, hj2;
    hi2.x = __float2bfloat16(nix * SFOLD);
    hi2.y = __float2bfloat16(niy * SFOLD);
    hj2.x = __float2bfloat16(njx * SFOLD);
    hj2.y = __float2bfloat16(njy * SFOLD);
    *reinterpret_cast<__hip_bfloat162*>(zb + (size_t)r * DIM + lane * 2) = hi2;
    *reinterpret_cast<__hip_bfloat162*>(zb + (size_t)(r + BATCH) * DIM + lane * 2) = hj2;

    float d = nix * njx + niy * njy;
    #pragma unroll
    for (int m = 1; m < 64; m <<= 1) d += __shfl_xor(d, m, 64);

    __shared__ float red[4];
    if (lane == 0) red[w] = d;
    __syncthreads();
    if (threadIdx.x == 0)
        ps[blockIdx.x] = red[0] + red[1] + red[2] + red[3];
}

// ---------------------------------------------------------------------------
// Kernel 2: r6-exact similarity (best measured: 43.2 us).
// ---------------------------------------------------------------------------
__global__ __launch_bounds__(256, 2) void k_sim(const __hip_bfloat16* __restrict__ zb,
                                                float* __restrict__ rowsum) {
    const int t = threadIdx.x;
    const int w = t >> 6;
    const int lane = t & 63;
    const int lo = lane & 15, hi = lane >> 4;

    const int rowBlock = blockIdx.x >> 4;
    const int split    = blockIdx.x & (CS - 1);
    const int rowBase  = rowBlock * 256 + w * 64;

    const char* zbB = reinterpret_cast<const char*>(zb);

    bf16x8 a[4][4];
    #pragma unroll
    for (int i = 0; i < 4; ++i) {
        const char* rp = zbB + (size_t)(rowBase + i * 16 + lo) * 256 + hi * 16;
        #pragma unroll
        for (int ks = 0; ks < 4; ++ks)
            a[i][ks] = *reinterpret_cast<const bf16x8*>(rp + ks * 64);
    }

    float psum[4][4];
    #pragma unroll
    for (int i = 0; i < 4; ++i)
        #pragma unroll
        for (int p = 0; p < 4; ++p) psum[i][p] = 0.0f;

    for (int ct = 0; ct < 8; ++ct) {
        const int colBase = split * 512 + ct * 64;

        bf16x8 b[4][4];
        #pragma unroll
        for (int j = 0; j < 4; ++j) {
            const char* rp = zbB + (size_t)(colBase + j * 16 + lo) * 256 + hi * 16;
            #pragma unroll
            for (int ks = 0; ks < 4; ++ks)
                b[j][ks] = *reinterpret_cast<const bf16x8*>(rp + ks * 64);
        }

        f32x4 acc[4][4];
        #pragma unroll
        for (int i = 0; i < 4; ++i)
            #pragma unroll
            for (int j = 0; j < 4; ++j) acc[i][j] = (f32x4){0.f, 0.f, 0.f, 0.f};

        #pragma unroll
        for (int ks = 0; ks < 4; ++ks)
            #pragma unroll
            for (int i = 0; i < 4; ++i)
                #pragma unroll
                for (int j = 0; j < 4; ++j)
                    acc[i][j] = __builtin_amdgcn_mfma_f32_16x16x32_bf16(
                        a[i][ks], b[j][ks], acc[i][j], 0, 0, 0);

        const bool diagTile = (colBase == rowBase);
        #pragma unroll
        for (int i = 0; i < 4; ++i) {
            #pragma unroll
            for (int p = 0; p < 4; ++p) {
                float s = 0.0f;
                #pragma unroll
                for (int j = 0; j < 4; ++j) {
                    float e = exp2f(acc[i][j][p]);
                    if (diagTile && j == i && lo == hi * 4 + p) e = 0.0f;
                    s += e;
                }
                psum[i][p] += s;
            }
        }
    }

    #pragma unroll
    for (int i = 0; i < 4; ++i) {
        #pragma unroll
        for (int p = 0; p < 4; ++p) {
            float s = psum[i][p];
            s += __shfl_xor(s, 1, 64);
            s += __shfl_xor(s, 2, 64);
            s += __shfl_xor(s, 4, 64);
            s += __shfl_xor(s, 8, 64);
            if (lo == 0)
                atomicAdd(&rowsum[rowBase + i * 16 + hi * 4 + p], s);
        }
    }
}

// ---------------------------------------------------------------------------
// PROBE 1: MFMA stream only. Same grid, same MFMA count (512/wave),
// register-fed fragments, tiny store. Healthy prediction: ~2-3 us.
// ---------------------------------------------------------------------------
__global__ __launch_bounds__(256, 2) void k_p_mfma(float* __restrict__ scr) {
    const int t = threadIdx.x;
    bf16x8 a[4], b[4];
    #pragma unroll
    for (int i = 0; i < 4; ++i)
        #pragma unroll
        for (int k = 0; k < 8; ++k) {
            a[i][k] = (short)(t * 37 + i * 11 + k);
            b[i][k] = (short)(t * 13 + i * 7 + k * 3);
        }
    f32x4 acc[4][4];
    #pragma unroll
    for (int i = 0; i < 4; ++i)
        #pragma unroll
        for (int j = 0; j < 4; ++j) acc[i][j] = (f32x4){0.f, 0.f, 0.f, 0.f};

    for (int ct = 0; ct < 8; ++ct) {
        #pragma unroll
        for (int ks = 0; ks < 4; ++ks)
            #pragma unroll
            for (int i = 0; i < 4; ++i)
                #pragma unroll
                for (int j = 0; j < 4; ++j)
                    acc[i][j] = __builtin_amdgcn_mfma_f32_16x16x32_bf16(
                        a[i], b[j], acc[i][j], 0, 0, 0);
    }
    float s = 0.0f;
    #pragma unroll
    for (int i = 0; i < 4; ++i)
        #pragma unroll
        for (int j = 0; j < 4; ++j)
            s += acc[i][j][0] + acc[i][j][1] + acc[i][j][2] + acc[i][j][3];
    scr[blockIdx.x * 256 + t] = s;
}

// ---------------------------------------------------------------------------
// PROBE 2: exact r6 load pattern (A + 8 B-tiles), cheap integer combine,
// one store. No MFMA, no exp. Healthy prediction: ~4-6 us.
// ---------------------------------------------------------------------------
__global__ __launch_bounds__(256, 2) void k_p_loads(const __hip_bfloat16* __restrict__ zb,
                                                    int* __restrict__ scr) {
    const int t = threadIdx.x;
    const int w = t >> 6;
    const int lane = t & 63;
    const int lo = lane & 15, hi = lane >> 4;
    const int rowBlock = blockIdx.x >> 4;
    const int split    = blockIdx.x & (CS - 1);
    const int rowBase  = rowBlock * 256 + w * 64;
    const char* zbB = reinterpret_cast<const char*>(zb);

    int s = 0;
    #pragma unroll
    for (int i = 0; i < 4; ++i) {
        const char* rp = zbB + (size_t)(rowBase + i * 16 + lo) * 256 + hi * 16;
        #pragma unroll
        for (int ks = 0; ks < 4; ++ks) {
            bf16x8 v = *reinterpret_cast<const bf16x8*>(rp + ks * 64);
            #pragma unroll
            for (int k = 0; k < 8; ++k) s ^= (int)v[k];
        }
    }
    for (int ct = 0; ct < 8; ++ct) {
        const int colBase = split * 512 + ct * 64;
        #pragma unroll
        for (int j = 0; j < 4; ++j) {
            const char* rp = zbB + (size_t)(colBase + j * 16 + lo) * 256 + hi * 16;
            #pragma unroll
            for (int ks = 0; ks < 4; ++ks) {
                bf16x8 v = *reinterpret_cast<const bf16x8*>(rp + ks * 64);
                #pragma unroll
                for (int k = 0; k < 8; ++k) s ^= (int)v[k];
            }
        }
    }
    scr[blockIdx.x * 256 + t] = s;
}

// ---------------------------------------------------------------------------
// PROBE 3: exact r6 epilogue (512 exp2 + mask + adds + shuffle reduce +
// atomics), register-fed acc (runtime blockIdx/lane-dependent, not foldable).
// Healthy prediction: ~3-5 us.
// ---------------------------------------------------------------------------
__global__ __launch_bounds__(256, 2) void k_p_epi(float* __restrict__ rsclone) {
    const int t = threadIdx.x;
    const int w = t >> 6;
    const int lane = t & 63;
    const int lo = lane & 15, hi = lane >> 4;
    const int rowBase = ((blockIdx.x >> 4) & 31) * 256 + w * 64;
    const float base = (float)((int)(blockIdx.x & 63) - 32) * 0.01f +
                       (float)lane * 0.001f;

    float psum[4][4];
    #pragma unroll
    for (int i = 0; i < 4; ++i)
        #pragma unroll
        for (int p = 0; p < 4; ++p) psum[i][p] = 0.0f;

    for (int ct = 0; ct < 8; ++ct) {
        const int colBase = (blockIdx.x & (CS - 1)) * 512 + ct * 64;
        const bool diagTile = (colBase == rowBase);
        float cb = base + (float)ct * 0.05f;
        #pragma unroll
        for (int i = 0; i < 4; ++i) {
            #pragma unroll
            for (int p = 0; p < 4; ++p) {
                float s = 0.0f;
                #pragma unroll
                for (int j = 0; j < 4; ++j) {
                    float e = exp2f(cb + (float)(i * 4 + j) * 0.02f +
                                    (float)p * 0.007f);
                    if (diagTile && j == i && lo == hi * 4 + p) e = 0.0f;
                    s += e;
                }
                psum[i][p] += s;
            }
        }
    }

    #pragma unroll
    for (int i = 0; i < 4; ++i) {
        #pragma unroll
        for (int p = 0; p < 4; ++p) {
            float s = psum[i][p];
            s += __shfl_xor(s, 1, 64);
            s += __shfl_xor(s, 2, 64);
            s += __shfl_xor(s, 4, 64);
            s += __shfl_xor(s, 8, 64);
            if (lo == 0)
                atomicAdd(&rsclone[rowBase + i * 16 + hi * 4 + p], s);
        }
    }
}

// ---------------------------------------------------------------------------
// Kernel 3: loss = (sum_r log(rowsum[r]) - 2*INV_TEMP*possum) / TWO_B
// ---------------------------------------------------------------------------
__global__ __launch_bounds__(1024) void k_final(const float* __restrict__ rowsum,
                                                const float* __restrict__ ps,
                                                float* __restrict__ out) {
    __shared__ float redl[1024];
    __shared__ float redp[1024];
    const int t = threadIdx.x;

    float s = 0.0f;
    #pragma unroll
    for (int q = 0; q < TWO_B / 1024; ++q) s += logf(rowsum[t + q * 1024]);
    float p = ps[t];

    redl[t] = s;
    redp[t] = p;
    __syncthreads();
    #pragma unroll
    for (int off = 512; off > 0; off >>= 1) {
        if (t < off) {
            redl[t] += redl[t + off];
            redp[t] += redp[t + off];
        }
        __syncthreads();
    }
    if (t == 0)
        out[0] = (redl[0] - 2.0f * INV_TEMP * redp[0]) / (float)TWO_B;
}

// ---------------------------------------------------------------------------
extern "C" void kernel_launch(void* const* d_in, const int* in_sizes, int n_in,
                              void* d_out, int out_size, void* d_ws, size_t ws_size,
                              hipStream_t stream) {
    const float* zi = (const float*)d_in[0];
    const float* zj = (const float*)d_in[1];
    float* out = (float*)d_out;

    char* ws = (char*)d_ws;
    __hip_bfloat16* zb = (__hip_bfloat16*)ws;
    float* rowsum = (float*)(ws + RS_OFFSET);
    float* ps = (float*)(ws + PS_OFFSET);
    float* scr1 = (float*)(ws + PR_OFFSET);                 // 512 KB
    int*   scr2 = (int*)(ws + PR_OFFSET + (1 << 20));       // 512 KB
    float* scr3 = (float*)(ws + PR_OFFSET + (2 << 20));     // 32 KB (rs clone)

    k_normalize<<<BATCH / 4, 256, 0, stream>>>(zi, zj, zb, ps, rowsum);
    k_sim<<<(TWO_B / 256) * CS, 256, 0, stream>>>(zb, rowsum);

    // --- diagnostic probes (results unused; rocprof rows are the output) ---
    k_p_mfma<<<512, 256, 0, stream>>>(scr1);
    k_p_loads<<<512, 256, 0, stream>>>(zb, scr2);
    k_p_epi<<<512, 256, 0, stream>>>(scr3);

    k_final<<<1, 1024, 0, stream>>>(rowsum, ps, out);
}

// Round 15
// 50.834 us; speedup vs baseline: 2.6942x; 2.1569x over previous
//
#include <hip/hip_runtime.h>
#include <hip/hip_bf16.h>

// Problem constants
#define BATCH   4096
#define TWO_B   8192
#define DIM     128
#define INV_TEMP 2.0f      // 1/TEMP, TEMP=0.5
// sqrt(INV_TEMP * log2(e)) folded into the stored bf16 vectors -> MFMA acc
// comes out as sim * INV_TEMP * log2(e); epilogue is a bare exp2.
#define SFOLD 1.6986436f   // sqrt(2.8853900817779268)

typedef __attribute__((ext_vector_type(8))) short bf16x8;   // 8 bf16 = 4 VGPRs
typedef __attribute__((ext_vector_type(4))) float f32x4;

#define CS 16              // col splits; each wave: 64 rows x 512 cols

// Workspace layout (bytes):
//   zb     : __hip_bfloat16[TWO_B*DIM]  [0, 2097152)   pre-scaled by SFOLD
//   rowsum : float[TWO_B]               zeroed by k_normalize
//   ps     : float[1024]                per-block possum partials
#define ZB_BYTES   (TWO_B * DIM * 2)
#define RS_OFFSET  ZB_BYTES
#define PS_OFFSET  (RS_OFFSET + TWO_B * 4)

// ---------------------------------------------------------------------------
// Kernel 1: L2-normalize rows of zi AND zj (paired), write bf16 z rows scaled
// by SFOLD, write per-block possum partial, and zero rowsum (8 floats/block).
// ---------------------------------------------------------------------------
__global__ __launch_bounds__(256) void k_normalize(const float* __restrict__ zi,
                                                   const float* __restrict__ zj,
                                                   __hip_bfloat16* __restrict__ zb,
                                                   float* __restrict__ ps,
                                                   float* __restrict__ rowsum) {
    int w = threadIdx.x >> 6;
    int lane = threadIdx.x & 63;
    int r = blockIdx.x * 4 + w;                       // [0, BATCH)

    if (threadIdx.x < 8) rowsum[blockIdx.x * 8 + threadIdx.x] = 0.0f;

    float2 vi = *reinterpret_cast<const float2*>(zi + (size_t)r * DIM + lane * 2);
    float2 vj = *reinterpret_cast<const float2*>(zj + (size_t)r * DIM + lane * 2);
    float ssi = vi.x * vi.x + vi.y * vi.y;
    float ssj = vj.x * vj.x + vj.y * vj.y;
    #pragma unroll
    for (int m = 1; m < 64; m <<= 1) {
        ssi += __shfl_xor(ssi, m, 64);
        ssj += __shfl_xor(ssj, m, 64);
    }
    float invi = 1.0f / fmaxf(sqrtf(ssi), 1e-12f);
    float invj = 1.0f / fmaxf(sqrtf(ssj), 1e-12f);

    float nix = vi.x * invi, niy = vi.y * invi;
    float njx = vj.x * invj, njy = vj.y * invj;

    __hip_bfloat162 hi2, hj2;
    hi2.x = __float2bfloat16(nix * SFOLD);
    hi2.y = __float2bfloat16(niy * SFOLD);
    hj2.x = __float2bfloat16(njx * SFOLD);
    hj2.y = __float2bfloat16(njy * SFOLD);
    *reinterpret_cast<__hip_bfloat162*>(zb + (size_t)r * DIM + lane * 2) = hi2;
    *reinterpret_cast<__hip_bfloat162*>(zb + (size_t)(r + BATCH) * DIM + lane * 2) = hj2;

    float d = nix * njx + niy * njy;
    #pragma unroll
    for (int m = 1; m < 64; m <<= 1) d += __shfl_xor(d, m, 64);

    __shared__ float red[4];
    if (lane == 0) red[w] = d;
    __syncthreads();
    if (threadIdx.x == 0)
        ps[blockIdx.x] = red[0] + red[1] + red[2] + red[3];
}

// ---------------------------------------------------------------------------
// Kernel 2: r6 structure + ANTI-CONVOY changes:
//  (a) wave-staggered column windows: wave w visits windows ((ct + 2w) & 7),
//      so the block's 4 waves are always in DIFFERENT phases (loads vs MFMA
//      vs exp2) and the CU pipes overlap across waves instead of serializing.
//      (r14 probes: loads/MFMA/epi each ~19 us isolated, ~additive in k_sim
//      => phase convoying.) L1 reuse preserved: all 8 windows stay resident.
//  (b) s_setprio(1) around the MFMA cluster (T5: pays with role diversity).
//  (c) rolled ct loop (unroll 1) to cut straight-line code mass.
// MFMA C/D layout (m89): col = lane&15, row = (lane>>4)*4 + reg.
// ---------------------------------------------------------------------------
__global__ __launch_bounds__(256, 2) void k_sim(const __hip_bfloat16* __restrict__ zb,
                                                float* __restrict__ rowsum) {
    const int t = threadIdx.x;
    const int w = t >> 6;
    const int lane = t & 63;
    const int lo = lane & 15, hi = lane >> 4;

    const int rowBlock = blockIdx.x >> 4;
    const int split    = blockIdx.x & (CS - 1);
    const int rowBase  = rowBlock * 256 + w * 64;

    const char* zbB = reinterpret_cast<const char*>(zb);

    bf16x8 a[4][4];
    #pragma unroll
    for (int i = 0; i < 4; ++i) {
        const char* rp = zbB + (size_t)(rowBase + i * 16 + lo) * 256 + hi * 16;
        #pragma unroll
        for (int ks = 0; ks < 4; ++ks)
            a[i][ks] = *reinterpret_cast<const bf16x8*>(rp + ks * 64);
    }

    float psum[4][4];
    #pragma unroll
    for (int i = 0; i < 4; ++i)
        #pragma unroll
        for (int p = 0; p < 4; ++p) psum[i][p] = 0.0f;

    #pragma unroll 1
    for (int ct = 0; ct < 8; ++ct) {
        // wave-staggered window order (anti-convoy)
        const int win = (ct + 2 * w) & 7;
        const int colBase = split * 512 + win * 64;

        bf16x8 b[4][4];
        #pragma unroll
        for (int j = 0; j < 4; ++j) {
            const char* rp = zbB + (size_t)(colBase + j * 16 + lo) * 256 + hi * 16;
            #pragma unroll
            for (int ks = 0; ks < 4; ++ks)
                b[j][ks] = *reinterpret_cast<const bf16x8*>(rp + ks * 64);
        }

        f32x4 acc[4][4];
        #pragma unroll
        for (int i = 0; i < 4; ++i)
            #pragma unroll
            for (int j = 0; j < 4; ++j) acc[i][j] = (f32x4){0.f, 0.f, 0.f, 0.f};

        __builtin_amdgcn_s_setprio(1);
        #pragma unroll
        for (int ks = 0; ks < 4; ++ks)
            #pragma unroll
            for (int i = 0; i < 4; ++i)
                #pragma unroll
                for (int j = 0; j < 4; ++j)
                    acc[i][j] = __builtin_amdgcn_mfma_f32_16x16x32_bf16(
                        a[i][ks], b[j][ks], acc[i][j], 0, 0, 0);
        __builtin_amdgcn_s_setprio(0);

        const bool diagTile = (colBase == rowBase);
        #pragma unroll
        for (int i = 0; i < 4; ++i) {
            #pragma unroll
            for (int p = 0; p < 4; ++p) {
                float s = 0.0f;
                #pragma unroll
                for (int j = 0; j < 4; ++j) {
                    float e = exp2f(acc[i][j][p]);
                    if (diagTile && j == i && lo == hi * 4 + p) e = 0.0f;
                    s += e;
                }
                psum[i][p] += s;
            }
        }
    }

    #pragma unroll
    for (int i = 0; i < 4; ++i) {
        #pragma unroll
        for (int p = 0; p < 4; ++p) {
            float s = psum[i][p];
            s += __shfl_xor(s, 1, 64);
            s += __shfl_xor(s, 2, 64);
            s += __shfl_xor(s, 4, 64);
            s += __shfl_xor(s, 8, 64);
            if (lo == 0)
                atomicAdd(&rowsum[rowBase + i * 16 + hi * 4 + p], s);
        }
    }
}

// ---------------------------------------------------------------------------
// Kernel 3: loss = (sum_r log(rowsum[r]) - 2*INV_TEMP*possum) / TWO_B
// ---------------------------------------------------------------------------
__global__ __launch_bounds__(1024) void k_final(const float* __restrict__ rowsum,
                                                const float* __restrict__ ps,
                                                float* __restrict__ out) {
    __shared__ float redl[1024];
    __shared__ float redp[1024];
    const int t = threadIdx.x;

    float s = 0.0f;
    #pragma unroll
    for (int q = 0; q < TWO_B / 1024; ++q) s += logf(rowsum[t + q * 1024]);
    float p = ps[t];

    redl[t] = s;
    redp[t] = p;
    __syncthreads();
    #pragma unroll
    for (int off = 512; off > 0; off >>= 1) {
        if (t < off) {
            redl[t] += redl[t + off];
            redp[t] += redp[t + off];
        }
        __syncthreads();
    }
    if (t == 0)
        out[0] = (redl[0] - 2.0f * INV_TEMP * redp[0]) / (float)TWO_B;
}

// ---------------------------------------------------------------------------
extern "C" void kernel_launch(void* const* d_in, const int* in_sizes, int n_in,
                              void* d_out, int out_size, void* d_ws, size_t ws_size,
                              hipStream_t stream) {
    const float* zi = (const float*)d_in[0];
    const float* zj = (const float*)d_in[1];
    float* out = (float*)d_out;

    char* ws = (char*)d_ws;
    __hip_bfloat16* zb = (__hip_bfloat16*)ws;
    float* rowsum = (float*)(ws + RS_OFFSET);
    float* ps = (float*)(ws + PS_OFFSET);

    k_normalize<<<BATCH / 4, 256, 0, stream>>>(zi, zj, zb, ps, rowsum);
    k_sim<<<(TWO_B / 256) * CS, 256, 0, stream>>>(zb, rowsum);
    k_final<<<1, 1024, 0, stream>>>(rowsum, ps, out);
}